// Round 1
// baseline (685.344 us; speedup 1.0000x reference)
//
#include <hip/hip_runtime.h>

// ---------------- problem constants ----------------
#define NEDGES   100000
#define NODE_DIM 128
#define CTX_DIM  256
#define OUT_DIM  256
#define IN_DIM   384
#define NCOEF    7
#define KTOT     3072          // 8*384 : [silu(x) | bsp_c0 .. bsp_c6]
#define BM       128           // edges per block
#define BK       64            // K-chunk
#define NCHUNK   (KTOT / BK)   // 48
#define THREADS  512           // 8 waves

// ---------------- LDS layout (ushort elements) ----------------
#define XSTR 392               // x row stride (384 + 8 pad)
#define ASTR 72                // A-tile row stride (64 + 8 pad)
#define BSTR 72                // B-tile row stride
#define OFF_X 0                                  // 128 x 392
#define OFF_A (BM * XSTR)                        // 128 x 72
#define OFF_B (OFF_A + BM * ASTR)                // 256 x 72
#define LDS_TOT (OFF_B + OUT_DIM * BSTR)         // 77824 ushorts = 155648 B (<160 KiB)

typedef __bf16 bf16x8 __attribute__((ext_vector_type(8)));
typedef float  f32x4  __attribute__((ext_vector_type(4)));

static __device__ __forceinline__ unsigned short f2bf(float f) {
    unsigned int u = __float_as_uint(f);
    u += 0x7FFFu + ((u >> 16) & 1u);   // RNE
    return (unsigned short)(u >> 16);
}
static __device__ __forceinline__ float bf2f(unsigned short h) {
    return __uint_as_float(((unsigned int)h) << 16);
}
// cardinal cubic B-spline on uniform knots, support t in (0,4)
static __device__ __forceinline__ float n3(float t) {
    float s  = fabsf(t - 2.0f);
    float p1 = (0.5f * s - 1.0f) * s * s + 0.66666667f;  // s in [0,1)
    float d  = 2.0f - s;
    float p2 = d * d * d * (1.0f / 6.0f);                // s in [1,2)
    return s < 1.0f ? p1 : (s < 2.0f ? p2 : 0.0f);
}
static __device__ __forceinline__ float silu(float x) {
    return x / (1.0f + __expf(-x));
}

// ---------------- weight prep: W bf16 [256][3072] ----------------
__global__ void prep_w_kernel(const float* __restrict__ base_w,
                              const float* __restrict__ spline_w,
                              const float* __restrict__ spline_s,
                              unsigned short* __restrict__ Wbf)
{
    int col = blockIdx.x * 256 + threadIdx.x;   // 0..3071
    int o   = blockIdx.y;                       // 0..255
    int seg = col / IN_DIM;
    int i   = col - seg * IN_DIM;
    float w;
    if (seg == 0) {
        w = base_w[o * IN_DIM + i];
    } else {
        int bi = o * IN_DIM + i;
        w = spline_w[(size_t)bi * NCOEF + (seg - 1)] * spline_s[bi];
    }
    Wbf[(size_t)o * KTOT + col] = f2bf(w);
}

// ---------------- fused kernel ----------------
template <bool PRE>
__global__ __launch_bounds__(THREADS, 2)
void fused_pair_kan(const float* __restrict__ node_emb,
                    const float* __restrict__ ctx_emb,
                    const int*   __restrict__ pair,
                    const float* __restrict__ ctx_w,
                    const float* __restrict__ ctx_b,
                    const float* __restrict__ base_w,
                    const float* __restrict__ spline_w,
                    const float* __restrict__ spline_s,
                    const float* __restrict__ grid,
                    const unsigned short* __restrict__ Wbf,
                    float* __restrict__ out)
{
    __shared__ unsigned short smem[LDS_TOT];

    const int tid    = threadIdx.x;
    const int e_base = blockIdx.x * BM;
    const int wid    = tid >> 6;
    const int lan    = tid & 63;
    const int lrow   = lan & 15;
    const int lquad  = lan >> 4;

    // ---- phase 0a: gather subj/obj rows -> x[:, 0:256] ----
    #pragma unroll
    for (int it = 0; it < 16; ++it) {
        int id    = it * THREADS + tid;       // 0..8191 = 2 lists * 128 e * 32 f4
        int lane4 = id & 31;
        int e     = (id >> 5) & 127;
        int which = id >> 12;                 // 0 subj, 1 obj
        int eg = e_base + e; if (eg >= NEDGES) eg = NEDGES - 1;
        int node = pair[eg * 2 + which];
        const float4 v = *(const float4*)(node_emb + (size_t)node * NODE_DIM + lane4 * 4);
        *(ushort4*)&smem[OFF_X + e * XSTR + which * NODE_DIM + lane4 * 4] =
            make_ushort4(f2bf(v.x), f2bf(v.y), f2bf(v.z), f2bf(v.w));
    }

    // ---- phase 0b: ctx = ctx_emb @ ctx_w^T + b  -> x[:, 256:384] ----
    {
        f32x4 cacc[4][2];
        #pragma unroll
        for (int a = 0; a < 4; ++a)
            #pragma unroll
            for (int b = 0; b < 2; ++b) { f32x4 z = {0.f,0.f,0.f,0.f}; cacc[a][b] = z; }

        const int m0 = (wid & 1) * 64;
        const int n0 = (wid >> 1) * 32;

        for (int kc = 0; kc < 4; ++kc) {
            #pragma unroll
            for (int it = 0; it < 4; ++it) {
                int id = it * THREADS + tid;   // 0..2047
                int r  = id >> 4;              // 0..127
                int c4 = id & 15;
                int eg = e_base + r; if (eg >= NEDGES) eg = NEDGES - 1;
                float4 v = *(const float4*)(ctx_emb + (size_t)eg * CTX_DIM + kc * 64 + c4 * 4);
                *(ushort4*)&smem[OFF_A + r * ASTR + c4 * 4] =
                    make_ushort4(f2bf(v.x), f2bf(v.y), f2bf(v.z), f2bf(v.w));
                float4 w = *(const float4*)(ctx_w + (size_t)r * CTX_DIM + kc * 64 + c4 * 4);
                *(ushort4*)&smem[OFF_B + r * BSTR + c4 * 4] =
                    make_ushort4(f2bf(w.x), f2bf(w.y), f2bf(w.z), f2bf(w.w));
            }
            __syncthreads();
            #pragma unroll
            for (int ks = 0; ks < 2; ++ks) {
                int koff = ks * 32 + lquad * 8;
                bf16x8 af[4], bfr[2];
                #pragma unroll
                for (int mt = 0; mt < 4; ++mt)
                    af[mt] = *(const bf16x8*)&smem[OFF_A + (m0 + mt*16 + lrow) * ASTR + koff];
                #pragma unroll
                for (int nt = 0; nt < 2; ++nt)
                    bfr[nt] = *(const bf16x8*)&smem[OFF_B + (n0 + nt*16 + lrow) * BSTR + koff];
                #pragma unroll
                for (int mt = 0; mt < 4; ++mt)
                    #pragma unroll
                    for (int nt = 0; nt < 2; ++nt)
                        cacc[mt][nt] = __builtin_amdgcn_mfma_f32_16x16x32_bf16(
                            af[mt], bfr[nt], cacc[mt][nt], 0, 0, 0);
            }
            __syncthreads();
        }
        // write ctx (+bias) into x[:, 256:384] as bf16
        #pragma unroll
        for (int mt = 0; mt < 4; ++mt)
            #pragma unroll
            for (int nt = 0; nt < 2; ++nt)
                #pragma unroll
                for (int r = 0; r < 4; ++r) {
                    int row = m0 + mt*16 + lquad*4 + r;
                    int col = n0 + nt*16 + lrow;
                    float v = cacc[mt][nt][r] + ctx_b[col];
                    smem[OFF_X + row * XSTR + 256 + col] = f2bf(v);
                }
    }
    __syncthreads();

    // ---- phase 1: out = A(x) @ W^T, K = 3072 ----
    const float g0   = grid[0];
    const float hinv = 1.0f / (grid[1] - grid[0]);

    f32x4 acc[4][4];
    #pragma unroll
    for (int a = 0; a < 4; ++a)
        #pragma unroll
        for (int b = 0; b < 4; ++b) { f32x4 z = {0.f,0.f,0.f,0.f}; acc[a][b] = z; }

    const int m0 = (wid & 1) * 64;
    const int n0 = (wid >> 1) * 64;

    for (int kb = 0; kb < NCHUNK; ++kb) {
        const int seg = kb / 6;              // 0 = silu, 1..7 = spline coef seg-1
        const int i0  = (kb - seg * 6) * BK; // offset within 384

        // B-tile global loads first (in flight during A-gen VALU)
        uint4 wv[4];
        if (PRE) {
            #pragma unroll
            for (int it = 0; it < 4; ++it) {
                int id = it * THREADS + tid;
                int o  = id >> 3;
                int v8 = id & 7;
                wv[it] = *(const uint4*)(Wbf + (size_t)o * KTOT + kb * BK + v8 * 8);
            }
        }

        // A-tile generation from x in LDS
        #pragma unroll
        for (int it = 0; it < 4; ++it) {
            int id = it * THREADS + tid;     // 0..2047
            int e  = id >> 4;
            int q  = id & 15;
            ushort4 xv = *(const ushort4*)&smem[OFF_X + e * XSTR + i0 + q * 4];
            float x0 = bf2f(xv.x), x1 = bf2f(xv.y), x2 = bf2f(xv.z), x3 = bf2f(xv.w);
            unsigned short r0, r1, r2, r3;
            if (seg == 0) {
                r0 = f2bf(silu(x0)); r1 = f2bf(silu(x1));
                r2 = f2bf(silu(x2)); r3 = f2bf(silu(x3));
            } else {
                const float cf = (float)(seg - 1);
                r0 = f2bf(n3((x0 - g0) * hinv - cf));
                r1 = f2bf(n3((x1 - g0) * hinv - cf));
                r2 = f2bf(n3((x2 - g0) * hinv - cf));
                r3 = f2bf(n3((x3 - g0) * hinv - cf));
            }
            *(ushort4*)&smem[OFF_A + e * ASTR + q * 4] = make_ushort4(r0, r1, r2, r3);
        }

        // B-tile into LDS
        if (PRE) {
            #pragma unroll
            for (int it = 0; it < 4; ++it) {
                int id = it * THREADS + tid;
                int o  = id >> 3;
                int v8 = id & 7;
                *(uint4*)&smem[OFF_B + o * BSTR + v8 * 8] = wv[it];
            }
        } else {
            #pragma unroll
            for (int it = 0; it < 4; ++it) {
                int id = it * THREADS + tid;
                int o  = id >> 4;
                int q  = id & 15;
                unsigned short r0, r1, r2, r3;
                if (seg == 0) {
                    const float4 w = *(const float4*)(base_w + (size_t)o * IN_DIM + i0 + q * 4);
                    r0 = f2bf(w.x); r1 = f2bf(w.y); r2 = f2bf(w.z); r3 = f2bf(w.w);
                } else {
                    int c  = seg - 1;
                    int bi = o * IN_DIM + i0 + q * 4;
                    r0 = f2bf(spline_w[(size_t)(bi    ) * NCOEF + c] * spline_s[bi    ]);
                    r1 = f2bf(spline_w[(size_t)(bi + 1) * NCOEF + c] * spline_s[bi + 1]);
                    r2 = f2bf(spline_w[(size_t)(bi + 2) * NCOEF + c] * spline_s[bi + 2]);
                    r3 = f2bf(spline_w[(size_t)(bi + 3) * NCOEF + c] * spline_s[bi + 3]);
                }
                *(ushort4*)&smem[OFF_B + o * BSTR + q * 4] = make_ushort4(r0, r1, r2, r3);
            }
        }
        __syncthreads();

        // MFMA over the chunk
        #pragma unroll
        for (int ks = 0; ks < 2; ++ks) {
            int koff = ks * 32 + lquad * 8;
            bf16x8 af[4], bfr[4];
            #pragma unroll
            for (int mt = 0; mt < 4; ++mt)
                af[mt] = *(const bf16x8*)&smem[OFF_A + (m0 + mt*16 + lrow) * ASTR + koff];
            #pragma unroll
            for (int nt = 0; nt < 4; ++nt)
                bfr[nt] = *(const bf16x8*)&smem[OFF_B + (n0 + nt*16 + lrow) * BSTR + koff];
            #pragma unroll
            for (int mt = 0; mt < 4; ++mt)
                #pragma unroll
                for (int nt = 0; nt < 4; ++nt)
                    acc[mt][nt] = __builtin_amdgcn_mfma_f32_16x16x32_bf16(
                        af[mt], bfr[nt], acc[mt][nt], 0, 0, 0);
        }
        __syncthreads();
    }

    // ---- epilogue: C row = edge (m), col = out (n) ----
    #pragma unroll
    for (int mt = 0; mt < 4; ++mt) {
        #pragma unroll
        for (int r = 0; r < 4; ++r) {
            int row = m0 + mt*16 + lquad*4 + r;
            int eg  = e_base + row;
            if (eg < NEDGES) {
                float* op = out + (size_t)eg * OUT_DIM + n0 + lrow;
                #pragma unroll
                for (int nt = 0; nt < 4; ++nt)
                    op[nt * 16] = acc[mt][nt][r];
            }
        }
    }
}

// ---------------- launch ----------------
extern "C" void kernel_launch(void* const* d_in, const int* in_sizes, int n_in,
                              void* d_out, int out_size, void* d_ws, size_t ws_size,
                              hipStream_t stream)
{
    const float* node_emb = (const float*)d_in[0];
    const float* ctx_emb  = (const float*)d_in[1];
    const int*   pair     = (const int*)d_in[2];
    const float* ctx_w    = (const float*)d_in[3];
    const float* ctx_b    = (const float*)d_in[4];
    const float* base_w   = (const float*)d_in[5];
    const float* spline_w = (const float*)d_in[6];
    const float* spline_s = (const float*)d_in[7];
    const float* grid     = (const float*)d_in[8];
    float* out = (float*)d_out;

    const int nblk = (NEDGES + BM - 1) / BM;   // 782
    const size_t wbytes = (size_t)OUT_DIM * KTOT * sizeof(unsigned short);

    if (ws_size >= wbytes) {
        unsigned short* Wbf = (unsigned short*)d_ws;
        prep_w_kernel<<<dim3(KTOT / 256, OUT_DIM), 256, 0, stream>>>(
            base_w, spline_w, spline_s, Wbf);
        fused_pair_kan<true><<<nblk, THREADS, 0, stream>>>(
            node_emb, ctx_emb, pair, ctx_w, ctx_b, base_w, spline_w, spline_s, grid, Wbf, out);
    } else {
        fused_pair_kan<false><<<nblk, THREADS, 0, stream>>>(
            node_emb, ctx_emb, pair, ctx_w, ctx_b, base_w, spline_w, spline_s, grid, nullptr, out);
    }
}

// Round 2
// 500.634 us; speedup vs baseline: 1.3690x; 1.3690x over previous
//
#include <hip/hip_runtime.h>

// ---------------- problem constants ----------------
#define NEDGES   100000
#define NODE_DIM 128
#define CTX_DIM  256
#define OUT_DIM  256
#define IN_DIM   384
#define NCOEF    7
#define KTOT     3072          // 8*384 : [silu(x) | bsp_c0 .. bsp_c6]
#define BM       128           // edges per block
#define BK       64            // K-chunk
#define THREADS  512           // 8 waves

typedef __bf16 bf16x8 __attribute__((ext_vector_type(8)));
typedef float  f32x4  __attribute__((ext_vector_type(4)));

static __device__ __forceinline__ unsigned short f2bf(float f) {
    unsigned int u = __float_as_uint(f);
    u += 0x7FFFu + ((u >> 16) & 1u);   // RNE
    return (unsigned short)(u >> 16);
}
static __device__ __forceinline__ float bf2f(unsigned short h) {
    return __uint_as_float(((unsigned int)h) << 16);
}
static __device__ __forceinline__ unsigned int pkbf(float a, float b) {
    unsigned int ua = __float_as_uint(a), ub = __float_as_uint(b);
    ua += 0x7FFFu + ((ua >> 16) & 1u);
    ub += 0x7FFFu + ((ub >> 16) & 1u);
    return (ua >> 16) | (ub & 0xFFFF0000u);
}
static __device__ __forceinline__ float silu(float x) {
    return x / (1.0f + __expf(-x));
}
// cardinal cubic B-spline, argument pre-shifted: d2 = t - 2 (support |d2|<2)
static __device__ __forceinline__ float n3c(float d2) {
    float a  = fabsf(d2);
    float t1 = fmaf(0.5f, a, -1.0f);
    float s2 = d2 * d2;
    float p1 = fmaf(t1, s2, 0.66666667f);
    float dd = fmaxf(2.0f - a, 0.0f);          // clamps tail to 0
    float p2 = dd * dd * (dd * (1.0f / 6.0f));
    return a < 1.0f ? p1 : p2;
}
static __device__ __forceinline__ float n3(float t) {   // legacy (fallback path)
    return n3c(t - 2.0f);
}

static __device__ __forceinline__ void glds16(const unsigned short* g, unsigned short* l) {
    __builtin_amdgcn_global_load_lds(
        (const __attribute__((address_space(1))) void*)g,
        (__attribute__((address_space(3))) void*)l, 16, 0, 0);
}

// =====================================================================
// NEW PATH: prep_w_swz + build_x + kan_gemm   (needs ws >= ~79 MB)
// =====================================================================

// W stored chunk-major, XOR-swizzled: chunk c = p*8 + seg covers K-cols
// seg*384 + p*64 .. +63.  Within chunk: [o][ (k8 ^ (o&7))*8 + j ]
__global__ void prep_w_swz(const float* __restrict__ base_w,
                           const float* __restrict__ spline_w,
                           const float* __restrict__ spline_s,
                           unsigned short* __restrict__ Wsw)
{
    int gc = blockIdx.x * 256 + threadIdx.x;   // 0..3071
    int o  = blockIdx.y;                       // 0..255
    int seg = gc / IN_DIM;
    int i   = gc - seg * IN_DIM;
    float w;
    if (seg == 0) w = base_w[o * IN_DIM + i];
    else {
        int bi = o * IN_DIM + i;
        w = spline_w[(size_t)bi * NCOEF + (seg - 1)] * spline_s[bi];
    }
    int p  = i >> 6;
    int k8 = (i >> 3) & 7;
    int j  = i & 7;
    int c  = p * 8 + seg;
    Wsw[(size_t)c * (OUT_DIM * BK) + o * BK + ((k8 ^ (o & 7)) << 3) + j] = f2bf(w);
}

// ---- K1: x = [bf16(subj) | bf16(obj) | bf16(ctx @ ctx_w^T + b)] -> ws ----
#define K1STR 72
__global__ __launch_bounds__(THREADS, 2)
void build_x(const float* __restrict__ node_emb,
             const float* __restrict__ ctx_emb,
             const int*   __restrict__ pair,
             const float* __restrict__ ctx_w,
             const float* __restrict__ ctx_b,
             unsigned short* __restrict__ Xbf)
{
    __shared__ unsigned short sm[2 * 128 * K1STR];   // Ae | Bw
    const int tid    = threadIdx.x;
    const int e_base = blockIdx.x * BM;
    const int wid    = tid >> 6;
    const int lan    = tid & 63;
    const int lrow   = lan & 15;
    const int lquad  = lan >> 4;

    // gather subj/obj -> x[:,0:256]
    #pragma unroll
    for (int it = 0; it < 16; ++it) {
        int id    = it * THREADS + tid;   // (e*2+which)*32 + f4
        int f4    = id & 31;
        int which = (id >> 5) & 1;
        int e     = id >> 6;
        int eg = e_base + e; if (eg >= NEDGES) eg = NEDGES - 1;
        int node = pair[eg * 2 + which];
        float4 v = *(const float4*)(node_emb + (size_t)node * NODE_DIM + f4 * 4);
        *(uint2*)&Xbf[(size_t)eg * IN_DIM + which * NODE_DIM + f4 * 4] =
            make_uint2(pkbf(v.x, v.y), pkbf(v.z, v.w));
    }

    // ctx GEMM: M=128 edges, N=128 outs, K=256
    f32x4 acc[4][2];
    #pragma unroll
    for (int a = 0; a < 4; ++a)
        #pragma unroll
        for (int b = 0; b < 2; ++b) { f32x4 z = {0.f,0.f,0.f,0.f}; acc[a][b] = z; }

    const int m0 = (wid & 1) * 64;
    const int n0 = (wid >> 1) * 32;

    for (int kc = 0; kc < 4; ++kc) {
        #pragma unroll
        for (int it = 0; it < 4; ++it) {
            int id = it * THREADS + tid;   // 0..2047
            int r  = id >> 4;              // 0..127
            int c4 = id & 15;
            int eg = e_base + r; if (eg >= NEDGES) eg = NEDGES - 1;
            float4 v = *(const float4*)(ctx_emb + (size_t)eg * CTX_DIM + kc * 64 + c4 * 4);
            *(uint2*)&sm[r * K1STR + c4 * 4] = make_uint2(pkbf(v.x, v.y), pkbf(v.z, v.w));
            float4 w = *(const float4*)(ctx_w + (size_t)r * CTX_DIM + kc * 64 + c4 * 4);
            *(uint2*)&sm[128 * K1STR + r * K1STR + c4 * 4] = make_uint2(pkbf(w.x, w.y), pkbf(w.z, w.w));
        }
        __syncthreads();
        #pragma unroll
        for (int ks = 0; ks < 2; ++ks) {
            int koff = ks * 32 + lquad * 8;
            bf16x8 af[4], bfr[2];
            #pragma unroll
            for (int mt = 0; mt < 4; ++mt)
                af[mt] = *(const bf16x8*)&sm[(m0 + mt*16 + lrow) * K1STR + koff];
            #pragma unroll
            for (int nt = 0; nt < 2; ++nt)
                bfr[nt] = *(const bf16x8*)&sm[128 * K1STR + (n0 + nt*16 + lrow) * K1STR + koff];
            #pragma unroll
            for (int mt = 0; mt < 4; ++mt)
                #pragma unroll
                for (int nt = 0; nt < 2; ++nt)
                    acc[mt][nt] = __builtin_amdgcn_mfma_f32_16x16x32_bf16(
                        af[mt], bfr[nt], acc[mt][nt], 0, 0, 0);
        }
        __syncthreads();
    }

    #pragma unroll
    for (int nt = 0; nt < 2; ++nt) {
        int col = n0 + nt * 16 + lrow;
        float cb = ctx_b[col];
        #pragma unroll
        for (int mt = 0; mt < 4; ++mt)
            #pragma unroll
            for (int r = 0; r < 4; ++r) {
                int row = m0 + mt * 16 + lquad * 4 + r;
                int eg = e_base + row; if (eg >= NEDGES) eg = NEDGES - 1;
                Xbf[(size_t)eg * IN_DIM + 256 + col] = f2bf(acc[mt][nt][r] + cb);
            }
    }
}

// ---- K2: out = A(x) @ W^T,  i0-outer / seg-inner, x in registers ----
#define ASTR  72
#define OFF_A 0
#define OFF_B (BM * ASTR)                    // 9216
#define K2_LDS (OFF_B + OUT_DIM * BK)        // 25600 ushorts = 51200 B

static __device__ __forceinline__ void mfma_chunk(const unsigned short* smem,
    f32x4 (&acc)[4][4], int m0, int n0, int lrow, int lquad)
{
    #pragma unroll
    for (int ks = 0; ks < 2; ++ks) {
        const int koff = ks * 32 + lquad * 8;
        const int k8   = ks * 4 + lquad;
        bf16x8 af[4], bfr[4];
        #pragma unroll
        for (int mt = 0; mt < 4; ++mt)
            af[mt] = *(const bf16x8*)&smem[OFF_A + (m0 + mt*16 + lrow) * ASTR + koff];
        #pragma unroll
        for (int nt = 0; nt < 4; ++nt) {
            int n = n0 + nt * 16 + lrow;
            bfr[nt] = *(const bf16x8*)&smem[OFF_B + n * BK + ((k8 ^ (n & 7)) << 3)];
        }
        #pragma unroll
        for (int mt = 0; mt < 4; ++mt)
            #pragma unroll
            for (int nt = 0; nt < 4; ++nt)
                acc[mt][nt] = __builtin_amdgcn_mfma_f32_16x16x32_bf16(
                    af[mt], bfr[nt], acc[mt][nt], 0, 0, 0);
    }
}

__global__ __launch_bounds__(THREADS, 4)
void kan_gemm(const unsigned short* __restrict__ Wsw,
              const unsigned short* __restrict__ Xbf,
              const float* __restrict__ grid,
              float* __restrict__ out)
{
    __shared__ unsigned short smem[K2_LDS];
    const int tid    = threadIdx.x;
    const int e_base = blockIdx.x * BM;
    const int wid    = tid >> 6;
    const int lan    = tid & 63;
    const int lrow   = lan & 15;
    const int lquad  = lan >> 4;
    const int m0     = (wid & 1) * 64;
    const int n0     = (wid >> 1) * 64;
    const int q      = tid & 15;

    const float g0   = grid[0];
    const float hinv = 1.0f / (grid[1] - grid[0]);
    const float cg   = -g0 * hinv - 2.0f;      // t-2 = x*hinv + cg

    const unsigned short* xrow[4];
    unsigned int awoff[4];
    #pragma unroll
    for (int it = 0; it < 4; ++it) {
        int e  = it * 32 + (tid >> 4);
        int eg = e_base + e; if (eg >= NEDGES) eg = NEDGES - 1;
        xrow[it]  = Xbf + (size_t)eg * IN_DIM;
        awoff[it] = OFF_A + e * ASTR + q * 4;
    }

    f32x4 acc[4][4];
    #pragma unroll
    for (int a = 0; a < 4; ++a)
        #pragma unroll
        for (int b = 0; b < 4; ++b) { f32x4 z = {0.f,0.f,0.f,0.f}; acc[a][b] = z; }

    for (int p = 0; p < 6; ++p) {
        const int i0 = p * 64;

        // B-tile for chunk (p, seg=0): global -> LDS DMA, overlaps VALU below
        {
            const unsigned short* wc = Wsw + (size_t)(p * 8) * (OUT_DIM * BK);
            #pragma unroll
            for (int it = 0; it < 4; ++it) {
                int id = it * THREADS + tid;
                glds16(wc + id * 8, &smem[OFF_B + id * 8]);
            }
        }

        // load x slice for this phase, compute silu (seg 0) + t-2 stash
        float tm2[16];
        #pragma unroll
        for (int it = 0; it < 4; ++it) {
            ushort4 xv = *(const ushort4*)(xrow[it] + i0 + q * 4);
            float x0 = bf2f(xv.x), x1 = bf2f(xv.y), x2 = bf2f(xv.z), x3 = bf2f(xv.w);
            *(uint2*)&smem[awoff[it]] =
                make_uint2(pkbf(silu(x0), silu(x1)), pkbf(silu(x2), silu(x3)));
            tm2[it*4+0] = fmaf(x0, hinv, cg);
            tm2[it*4+1] = fmaf(x1, hinv, cg);
            tm2[it*4+2] = fmaf(x2, hinv, cg);
            tm2[it*4+3] = fmaf(x3, hinv, cg);
        }
        __syncthreads();
        mfma_chunk(smem, acc, m0, n0, lrow, lquad);
        __syncthreads();

        for (int seg = 1; seg < 8; ++seg) {
            const unsigned short* wc = Wsw + (size_t)(p * 8 + seg) * (OUT_DIM * BK);
            #pragma unroll
            for (int it = 0; it < 4; ++it) {
                int id = it * THREADS + tid;
                glds16(wc + id * 8, &smem[OFF_B + id * 8]);
            }
            const float sf = (float)(seg - 1);
            #pragma unroll
            for (int it = 0; it < 4; ++it) {
                float r0 = n3c(tm2[it*4+0] - sf);
                float r1 = n3c(tm2[it*4+1] - sf);
                float r2 = n3c(tm2[it*4+2] - sf);
                float r3 = n3c(tm2[it*4+3] - sf);
                *(uint2*)&smem[awoff[it]] = make_uint2(pkbf(r0, r1), pkbf(r2, r3));
            }
            __syncthreads();
            mfma_chunk(smem, acc, m0, n0, lrow, lquad);
            __syncthreads();
        }
    }

    // epilogue: C row = edge (m), col = out (n)
    #pragma unroll
    for (int mt = 0; mt < 4; ++mt) {
        #pragma unroll
        for (int r = 0; r < 4; ++r) {
            int row = m0 + mt * 16 + lquad * 4 + r;
            int eg  = e_base + row;
            if (eg < NEDGES) {
                float* op = out + (size_t)eg * OUT_DIM + n0 + lrow;
                #pragma unroll
                for (int nt = 0; nt < 4; ++nt)
                    op[nt * 16] = acc[mt][nt][r];
            }
        }
    }
}

// =====================================================================
// FALLBACK PATH (round-1 kernel, known-good 570 us) for small ws
// =====================================================================
#define XSTR 392
#define FASTR 72
#define FBSTR 72
#define FOFF_X 0
#define FOFF_A (BM * XSTR)
#define FOFF_B (FOFF_A + BM * FASTR)
#define FLDS_TOT (FOFF_B + OUT_DIM * FBSTR)
#define NCHUNK (KTOT / BK)

__global__ void prep_w_kernel(const float* __restrict__ base_w,
                              const float* __restrict__ spline_w,
                              const float* __restrict__ spline_s,
                              unsigned short* __restrict__ Wbf)
{
    int col = blockIdx.x * 256 + threadIdx.x;
    int o   = blockIdx.y;
    int seg = col / IN_DIM;
    int i   = col - seg * IN_DIM;
    float w;
    if (seg == 0) w = base_w[o * IN_DIM + i];
    else {
        int bi = o * IN_DIM + i;
        w = spline_w[(size_t)bi * NCOEF + (seg - 1)] * spline_s[bi];
    }
    Wbf[(size_t)o * KTOT + col] = f2bf(w);
}

template <bool PRE>
__global__ __launch_bounds__(THREADS, 2)
void fused_pair_kan(const float* __restrict__ node_emb,
                    const float* __restrict__ ctx_emb,
                    const int*   __restrict__ pair,
                    const float* __restrict__ ctx_w,
                    const float* __restrict__ ctx_b,
                    const float* __restrict__ base_w,
                    const float* __restrict__ spline_w,
                    const float* __restrict__ spline_s,
                    const float* __restrict__ grid,
                    const unsigned short* __restrict__ Wbf,
                    float* __restrict__ out)
{
    __shared__ unsigned short smem[FLDS_TOT];
    const int tid    = threadIdx.x;
    const int e_base = blockIdx.x * BM;
    const int wid    = tid >> 6;
    const int lan    = tid & 63;
    const int lrow   = lan & 15;
    const int lquad  = lan >> 4;

    #pragma unroll
    for (int it = 0; it < 16; ++it) {
        int id    = it * THREADS + tid;
        int lane4 = id & 31;
        int e     = (id >> 5) & 127;
        int which = id >> 12;
        int eg = e_base + e; if (eg >= NEDGES) eg = NEDGES - 1;
        int node = pair[eg * 2 + which];
        const float4 v = *(const float4*)(node_emb + (size_t)node * NODE_DIM + lane4 * 4);
        *(ushort4*)&smem[FOFF_X + e * XSTR + which * NODE_DIM + lane4 * 4] =
            make_ushort4(f2bf(v.x), f2bf(v.y), f2bf(v.z), f2bf(v.w));
    }
    {
        f32x4 cacc[4][2];
        #pragma unroll
        for (int a = 0; a < 4; ++a)
            #pragma unroll
            for (int b = 0; b < 2; ++b) { f32x4 z = {0.f,0.f,0.f,0.f}; cacc[a][b] = z; }
        const int m0 = (wid & 1) * 64;
        const int n0 = (wid >> 1) * 32;
        for (int kc = 0; kc < 4; ++kc) {
            #pragma unroll
            for (int it = 0; it < 4; ++it) {
                int id = it * THREADS + tid;
                int r  = id >> 4;
                int c4 = id & 15;
                int eg = e_base + r; if (eg >= NEDGES) eg = NEDGES - 1;
                float4 v = *(const float4*)(ctx_emb + (size_t)eg * CTX_DIM + kc * 64 + c4 * 4);
                *(ushort4*)&smem[FOFF_A + r * FASTR + c4 * 4] =
                    make_ushort4(f2bf(v.x), f2bf(v.y), f2bf(v.z), f2bf(v.w));
                float4 w = *(const float4*)(ctx_w + (size_t)r * CTX_DIM + kc * 64 + c4 * 4);
                *(ushort4*)&smem[FOFF_B + r * FBSTR + c4 * 4] =
                    make_ushort4(f2bf(w.x), f2bf(w.y), f2bf(w.z), f2bf(w.w));
            }
            __syncthreads();
            #pragma unroll
            for (int ks = 0; ks < 2; ++ks) {
                int koff = ks * 32 + lquad * 8;
                bf16x8 af[4], bfr[2];
                #pragma unroll
                for (int mt = 0; mt < 4; ++mt)
                    af[mt] = *(const bf16x8*)&smem[FOFF_A + (m0 + mt*16 + lrow) * FASTR + koff];
                #pragma unroll
                for (int nt = 0; nt < 2; ++nt)
                    bfr[nt] = *(const bf16x8*)&smem[FOFF_B + (n0 + nt*16 + lrow) * FBSTR + koff];
                #pragma unroll
                for (int mt = 0; mt < 4; ++mt)
                    #pragma unroll
                    for (int nt = 0; nt < 2; ++nt)
                        cacc[mt][nt] = __builtin_amdgcn_mfma_f32_16x16x32_bf16(
                            af[mt], bfr[nt], cacc[mt][nt], 0, 0, 0);
            }
            __syncthreads();
        }
        #pragma unroll
        for (int mt = 0; mt < 4; ++mt)
            #pragma unroll
            for (int nt = 0; nt < 2; ++nt)
                #pragma unroll
                for (int r = 0; r < 4; ++r) {
                    int row = m0 + mt*16 + lquad*4 + r;
                    int col = n0 + nt*16 + lrow;
                    float v = cacc[mt][nt][r] + ctx_b[col];
                    smem[FOFF_X + row * XSTR + 256 + col] = f2bf(v);
                }
    }
    __syncthreads();

    const float g0   = grid[0];
    const float hinv = 1.0f / (grid[1] - grid[0]);

    f32x4 acc[4][4];
    #pragma unroll
    for (int a = 0; a < 4; ++a)
        #pragma unroll
        for (int b = 0; b < 4; ++b) { f32x4 z = {0.f,0.f,0.f,0.f}; acc[a][b] = z; }

    const int m0 = (wid & 1) * 64;
    const int n0 = (wid >> 1) * 64;

    for (int kb = 0; kb < NCHUNK; ++kb) {
        const int seg = kb / 6;
        const int i0  = (kb - seg * 6) * BK;
        uint4 wv[4];
        if (PRE) {
            #pragma unroll
            for (int it = 0; it < 4; ++it) {
                int id = it * THREADS + tid;
                int o  = id >> 3;
                int v8 = id & 7;
                wv[it] = *(const uint4*)(Wbf + (size_t)o * KTOT + kb * BK + v8 * 8);
            }
        }
        #pragma unroll
        for (int it = 0; it < 4; ++it) {
            int id = it * THREADS + tid;
            int e  = id >> 4;
            int qq = id & 15;
            ushort4 xv = *(const ushort4*)&smem[FOFF_X + e * XSTR + i0 + qq * 4];
            float x0 = bf2f(xv.x), x1 = bf2f(xv.y), x2 = bf2f(xv.z), x3 = bf2f(xv.w);
            unsigned short r0, r1, r2, r3;
            if (seg == 0) {
                r0 = f2bf(silu(x0)); r1 = f2bf(silu(x1));
                r2 = f2bf(silu(x2)); r3 = f2bf(silu(x3));
            } else {
                const float cf = (float)(seg - 1);
                r0 = f2bf(n3((x0 - g0) * hinv - cf));
                r1 = f2bf(n3((x1 - g0) * hinv - cf));
                r2 = f2bf(n3((x2 - g0) * hinv - cf));
                r3 = f2bf(n3((x3 - g0) * hinv - cf));
            }
            *(ushort4*)&smem[FOFF_A + e * FASTR + qq * 4] = make_ushort4(r0, r1, r2, r3);
        }
        if (PRE) {
            #pragma unroll
            for (int it = 0; it < 4; ++it) {
                int id = it * THREADS + tid;
                int o  = id >> 3;
                int v8 = id & 7;
                *(uint4*)&smem[FOFF_B + o * FBSTR + v8 * 8] = wv[it];
            }
        } else {
            #pragma unroll
            for (int it = 0; it < 4; ++it) {
                int id = it * THREADS + tid;
                int o  = id >> 4;
                int qq = id & 15;
                unsigned short r0, r1, r2, r3;
                if (seg == 0) {
                    const float4 w = *(const float4*)(base_w + (size_t)o * IN_DIM + i0 + qq * 4);
                    r0 = f2bf(w.x); r1 = f2bf(w.y); r2 = f2bf(w.z); r3 = f2bf(w.w);
                } else {
                    int c  = seg - 1;
                    int bi = o * IN_DIM + i0 + qq * 4;
                    r0 = f2bf(spline_w[(size_t)(bi    ) * NCOEF + c] * spline_s[bi    ]);
                    r1 = f2bf(spline_w[(size_t)(bi + 1) * NCOEF + c] * spline_s[bi + 1]);
                    r2 = f2bf(spline_w[(size_t)(bi + 2) * NCOEF + c] * spline_s[bi + 2]);
                    r3 = f2bf(spline_w[(size_t)(bi + 3) * NCOEF + c] * spline_s[bi + 3]);
                }
                *(ushort4*)&smem[FOFF_B + o * FBSTR + qq * 4] = make_ushort4(r0, r1, r2, r3);
            }
        }
        __syncthreads();
        #pragma unroll
        for (int ks = 0; ks < 2; ++ks) {
            int koff = ks * 32 + lquad * 8;
            bf16x8 af[4], bfr[4];
            #pragma unroll
            for (int mt = 0; mt < 4; ++mt)
                af[mt] = *(const bf16x8*)&smem[FOFF_A + (m0 + mt*16 + lrow) * FASTR + koff];
            #pragma unroll
            for (int nt = 0; nt < 4; ++nt)
                bfr[nt] = *(const bf16x8*)&smem[FOFF_B + (n0 + nt*16 + lrow) * FBSTR + koff];
            #pragma unroll
            for (int mt = 0; mt < 4; ++mt)
                #pragma unroll
                for (int nt = 0; nt < 4; ++nt)
                    acc[mt][nt] = __builtin_amdgcn_mfma_f32_16x16x32_bf16(
                        af[mt], bfr[nt], acc[mt][nt], 0, 0, 0);
        }
        __syncthreads();
    }

    #pragma unroll
    for (int mt = 0; mt < 4; ++mt) {
        #pragma unroll
        for (int r = 0; r < 4; ++r) {
            int row = m0 + mt*16 + lquad*4 + r;
            int eg  = e_base + row;
            if (eg < NEDGES) {
                float* op = out + (size_t)eg * OUT_DIM + n0 + lrow;
                #pragma unroll
                for (int nt = 0; nt < 4; ++nt)
                    op[nt * 16] = acc[mt][nt][r];
            }
        }
    }
}

// ---------------- launch ----------------
extern "C" void kernel_launch(void* const* d_in, const int* in_sizes, int n_in,
                              void* d_out, int out_size, void* d_ws, size_t ws_size,
                              hipStream_t stream)
{
    const float* node_emb = (const float*)d_in[0];
    const float* ctx_emb  = (const float*)d_in[1];
    const int*   pair     = (const int*)d_in[2];
    const float* ctx_w    = (const float*)d_in[3];
    const float* ctx_b    = (const float*)d_in[4];
    const float* base_w   = (const float*)d_in[5];
    const float* spline_w = (const float*)d_in[6];
    const float* spline_s = (const float*)d_in[7];
    const float* grid     = (const float*)d_in[8];
    float* out = (float*)d_out;

    const int nblk = (NEDGES + BM - 1) / BM;   // 782
    const size_t wbytes = (size_t)OUT_DIM * KTOT * sizeof(unsigned short);  // 1.57 MB
    const size_t xoff   = 2u * 1024u * 1024u;                               // bytes
    const size_t need   = xoff + (size_t)NEDGES * IN_DIM * sizeof(unsigned short);

    if (ws_size >= need) {
        unsigned short* Wsw = (unsigned short*)d_ws;
        unsigned short* Xbf = (unsigned short*)((char*)d_ws + xoff);
        prep_w_swz<<<dim3(KTOT / 256, OUT_DIM), 256, 0, stream>>>(base_w, spline_w, spline_s, Wsw);
        build_x<<<nblk, THREADS, 0, stream>>>(node_emb, ctx_emb, pair, ctx_w, ctx_b, Xbf);
        kan_gemm<<<nblk, THREADS, 0, stream>>>(Wsw, Xbf, grid, out);
    } else if (ws_size >= wbytes) {
        unsigned short* Wbf = (unsigned short*)d_ws;
        prep_w_kernel<<<dim3(KTOT / 256, OUT_DIM), 256, 0, stream>>>(base_w, spline_w, spline_s, Wbf);
        fused_pair_kan<true><<<nblk, THREADS, 0, stream>>>(
            node_emb, ctx_emb, pair, ctx_w, ctx_b, base_w, spline_w, spline_s, grid, Wbf, out);
    } else {
        fused_pair_kan<false><<<nblk, THREADS, 0, stream>>>(
            node_emb, ctx_emb, pair, ctx_w, ctx_b, base_w, spline_w, spline_s, grid, nullptr, out);
    }
}

// Round 3
// 436.073 us; speedup vs baseline: 1.5716x; 1.1480x over previous
//
#include <hip/hip_runtime.h>

// ---------------- problem constants ----------------
#define NEDGES   100000
#define NODE_DIM 128
#define CTX_DIM  256
#define OUT_DIM  256
#define IN_DIM   384
#define NCOEF    7

// kan_gemm2 tiling: K' = i*8 + slot, slot0=silu, slot1..7=spline c=slot-1
#define BM2      128
#define BK2      32            // 4 x-cols * 8 slots
#define NCH2     96            // IN_DIM / 4
#define THR2     512           // 8 waves

typedef __bf16 bf16x8 __attribute__((ext_vector_type(8)));
typedef float  f32x4  __attribute__((ext_vector_type(4)));

static __device__ __forceinline__ unsigned short f2bf(float f) {
    unsigned int u = __float_as_uint(f);
    u += 0x7FFFu + ((u >> 16) & 1u);   // RNE
    return (unsigned short)(u >> 16);
}
static __device__ __forceinline__ float bf2f(unsigned short h) {
    return __uint_as_float(((unsigned int)h) << 16);
}
static __device__ __forceinline__ unsigned int pkbf(float a, float b) {
    unsigned int ua = __float_as_uint(a), ub = __float_as_uint(b);
    ua += 0x7FFFu + ((ua >> 16) & 1u);
    ub += 0x7FFFu + ((ub >> 16) & 1u);
    return (ua >> 16) | (ub & 0xFFFF0000u);
}
static __device__ __forceinline__ float silu(float x) {
    return x / (1.0f + __expf(-x));
}
// cardinal cubic B-spline (fallback path)
static __device__ __forceinline__ float n3(float t) {
    float d2 = t - 2.0f;
    float a  = fabsf(d2);
    float p1 = fmaf(fmaf(0.5f, a, -1.0f), d2 * d2, 0.66666667f);
    float dd = fmaxf(2.0f - a, 0.0f);
    float p2 = dd * dd * (dd * (1.0f / 6.0f));
    return a < 1.0f ? p1 : p2;
}

static __device__ __forceinline__ void glds16(const unsigned short* g, unsigned short* l) {
    __builtin_amdgcn_global_load_lds(
        (const __attribute__((address_space(1))) void*)g,
        (__attribute__((address_space(3))) void*)l, 16, 0, 0);
}

// =====================================================================
// W prep: chunk-major [96][256 o][32 k], granule-permuted for LDS banks.
// chunk ch = i>>2 covers x-cols i = ch*4..+3; granule (16B = 8 slots of
// one (o,i)) at index p = o*4 + (((o>>1) + (i&3)) & 3)
// =====================================================================
__global__ void prep_w2(const float* __restrict__ base_w,
                        const float* __restrict__ spline_w,
                        const float* __restrict__ spline_s,
                        unsigned short* __restrict__ Wsw)
{
    int o = blockIdx.x;          // 0..255
    int i = threadIdx.x;         // 0..383
    int bi = o * IN_DIM + i;
    float sc = spline_s[bi];
    const float* sw = spline_w + (size_t)bi * NCOEF;
    uint4 v;
    v.x = pkbf(base_w[bi], sw[0] * sc);
    v.y = pkbf(sw[1] * sc, sw[2] * sc);
    v.z = pkbf(sw[3] * sc, sw[4] * sc);
    v.w = pkbf(sw[5] * sc, sw[6] * sc);
    int ch = i >> 2, g8 = i & 3;
    int p  = o * 4 + (((o >> 1) + g8) & 3);
    *(uint4*)(Wsw + (size_t)ch * (OUT_DIM * BK2) + p * 8) = v;
}

// =====================================================================
// build_x: Xbf[e][384] = [bf16(subj) | bf16(obj) | bf16(ctx@ctx_w^T + b)]
// =====================================================================
#define K1STR 72
#define BM   128
__global__ __launch_bounds__(512, 2)
void build_x(const float* __restrict__ node_emb,
             const float* __restrict__ ctx_emb,
             const int*   __restrict__ pair,
             const float* __restrict__ ctx_w,
             const float* __restrict__ ctx_b,
             unsigned short* __restrict__ Xbf)
{
    __shared__ unsigned short sm[2 * 128 * K1STR];
    const int tid    = threadIdx.x;
    const int e_base = blockIdx.x * BM;
    const int wid    = tid >> 6;
    const int lan    = tid & 63;
    const int lrow   = lan & 15;
    const int lquad  = lan >> 4;

    // gather subj/obj -> x[:,0:256]  (coalesced 512B row reads)
    #pragma unroll
    for (int it = 0; it < 16; ++it) {
        int id    = it * 512 + tid;
        int f4    = id & 31;
        int which = (id >> 5) & 1;
        int e     = id >> 6;
        int eg = e_base + e; if (eg >= NEDGES) eg = NEDGES - 1;
        int node = pair[eg * 2 + which];
        float4 v = *(const float4*)(node_emb + (size_t)node * NODE_DIM + f4 * 4);
        *(uint2*)&Xbf[(size_t)eg * IN_DIM + which * NODE_DIM + f4 * 4] =
            make_uint2(pkbf(v.x, v.y), pkbf(v.z, v.w));
    }

    // ctx GEMM: M=128 edges, N=128, K=256
    f32x4 acc[4][2];
    #pragma unroll
    for (int a = 0; a < 4; ++a)
        #pragma unroll
        for (int b = 0; b < 2; ++b) { f32x4 z = {0.f,0.f,0.f,0.f}; acc[a][b] = z; }

    const int m0 = (wid & 1) * 64;
    const int n0 = (wid >> 1) * 32;

    for (int kc = 0; kc < 4; ++kc) {
        #pragma unroll
        for (int it = 0; it < 4; ++it) {
            int id = it * 512 + tid;
            int r  = id >> 4;
            int c4 = id & 15;
            int eg = e_base + r; if (eg >= NEDGES) eg = NEDGES - 1;
            float4 v = *(const float4*)(ctx_emb + (size_t)eg * CTX_DIM + kc * 64 + c4 * 4);
            *(uint2*)&sm[r * K1STR + c4 * 4] = make_uint2(pkbf(v.x, v.y), pkbf(v.z, v.w));
            float4 w = *(const float4*)(ctx_w + (size_t)r * CTX_DIM + kc * 64 + c4 * 4);
            *(uint2*)&sm[128 * K1STR + r * K1STR + c4 * 4] = make_uint2(pkbf(w.x, w.y), pkbf(w.z, w.w));
        }
        __syncthreads();
        #pragma unroll
        for (int ks = 0; ks < 2; ++ks) {
            int koff = ks * 32 + lquad * 8;
            bf16x8 af[4], bfr[2];
            #pragma unroll
            for (int mt = 0; mt < 4; ++mt)
                af[mt] = *(const bf16x8*)&sm[(m0 + mt*16 + lrow) * K1STR + koff];
            #pragma unroll
            for (int nt = 0; nt < 2; ++nt)
                bfr[nt] = *(const bf16x8*)&sm[128 * K1STR + (n0 + nt*16 + lrow) * K1STR + koff];
            #pragma unroll
            for (int mt = 0; mt < 4; ++mt)
                #pragma unroll
                for (int nt = 0; nt < 2; ++nt)
                    acc[mt][nt] = __builtin_amdgcn_mfma_f32_16x16x32_bf16(
                        af[mt], bfr[nt], acc[mt][nt], 0, 0, 0);
        }
        __syncthreads();
    }

    // stage ctx result in LDS, then coalesced global write (fixes R2's
    // scattered 2B stores)
    #define ESTR 136
    #pragma unroll
    for (int nt = 0; nt < 2; ++nt) {
        int col = n0 + nt * 16 + lrow;
        float cb = ctx_b[col];
        #pragma unroll
        for (int mt = 0; mt < 4; ++mt)
            #pragma unroll
            for (int r = 0; r < 4; ++r) {
                int row = m0 + mt * 16 + lquad * 4 + r;
                sm[row * ESTR + col] = f2bf(acc[mt][nt][r] + cb);
            }
    }
    __syncthreads();
    #pragma unroll
    for (int it = 0; it < 8; ++it) {
        int id = it * 512 + tid;        // 0..4095 = 128 rows x 32 groups
        int row = id >> 5;
        int g   = id & 31;
        int eg = e_base + row; if (eg >= NEDGES) eg = NEDGES - 1;
        *(uint2*)&Xbf[(size_t)eg * IN_DIM + 256 + g * 4] = *(uint2*)&sm[row * ESTR + g * 4];
    }
}

// =====================================================================
// kan_gemm2: out = A(x) @ W^T with K-reordered A generated in-flight.
// dbuf A + dbuf B, one barrier per BK=32 chunk.
// =====================================================================
#define A2STR  40                          // 32 + 8 pad (ushorts)
#define A2SZ   (BM2 * A2STR)               // 5120
#define B2SZ   (OUT_DIM * BK2)             // 8192
#define OFF_A0 0
#define OFF_A1 A2SZ
#define OFF_B0 (2 * A2SZ)
#define OFF_B1 (2 * A2SZ + B2SZ)
#define LDS2   (2 * A2SZ + 2 * B2SZ)       // 26624 ush = 53248 B

// one x element -> 8 bf16 slots [silu | c0..c6], single b128 LDS write.
// spline: u=frac(t); 4 nonzero pieces Q0..Q3 positioned by 128-bit shift.
static __device__ __forceinline__ void gen_elem(
    unsigned short xh, float hinv, float b0, unsigned short* dst)
{
    float x  = bf2f(xh);
    float sl = silu(x);
    unsigned short slh = f2bf(sl);
    float t  = fmaf(x, hinv, b0);
    float jf = floorf(t);
    int   j0 = (int)jf;
    float u  = t - jf;
    float u2 = u * u, u3 = u2 * u;
    float Q0 = u3 * 0.16666667f;
    float d  = 1.0f - u;
    float Q3 = d * d * d * 0.16666667f;
    float Q1 = fmaf(0.5f, u + u2 - u3, 0.16666667f);
    float Q2 = fmaf(0.5f, u3, 0.66666667f - u2);
    // payload slots ascending: [Q3 @ g=j0-2, Q2, Q1, Q0 @ g=j0+1]
    unsigned plo = pkbf(Q3, Q2);
    unsigned phi = pkbf(Q1, Q0);
    unsigned long long P = ((unsigned long long)phi << 32) | plo;
    int sh = (j0 << 4) - 32;
    unsigned a  = (unsigned)sh;
    unsigned na = 0u - a;
    unsigned long long lo =
        (a  < 64u) ? (P << (a  & 63u)) : ((na < 64u) ? (P >> (na & 63u)) : 0ull);
    unsigned b2 = a - 64u;
    unsigned nb = 0u - b2;
    unsigned long long hi =
        (b2 < 64u) ? (P << (b2 & 63u)) : ((nb < 64u) ? (P >> (nb & 63u)) : 0ull);
    lo = (lo & ~0xFFFFull) | (unsigned long long)slh;   // slot0 = silu
    uint4 w;
    w.x = (unsigned)lo; w.y = (unsigned)(lo >> 32);
    w.z = (unsigned)hi; w.w = (unsigned)(hi >> 32);
    *(uint4*)dst = w;
}

__global__ __launch_bounds__(THR2, 4)
void kan_gemm2(const unsigned short* __restrict__ Wsw,
               const unsigned short* __restrict__ Xbf,
               const float* __restrict__ grid,
               float* __restrict__ out)
{
    __shared__ unsigned short smem[LDS2];
    const int tid    = threadIdx.x;
    const int e_base = blockIdx.x * BM2;
    const int wid    = tid >> 6;
    const int lan    = tid & 63;
    const int lrow   = lan & 15;
    const int lquad  = lan >> 4;
    const int m0     = (wid & 1) * 64;
    const int n0     = (wid >> 1) * 64;

    const float g0   = grid[0];
    const float hinv = 1.0f / (grid[1] - grid[0]);
    const float b0   = -g0 * hinv;

    // gen assignment: one elem/thread/chunk
    const int grow = tid >> 2;           // 0..127
    const int gcol = tid & 3;
    int geg = e_base + grow; if (geg >= NEDGES) geg = NEDGES - 1;
    const unsigned short* xp = Xbf + (size_t)geg * IN_DIM + gcol;
    const unsigned awr = grow * A2STR + gcol * 8;

    f32x4 acc[4][4];
    #pragma unroll
    for (int a = 0; a < 4; ++a)
        #pragma unroll
        for (int b = 0; b < 4; ++b) { f32x4 z = {0.f,0.f,0.f,0.f}; acc[a][b] = z; }

    unsigned short xc = xp[0];
    unsigned short xn = xp[4];

    // prologue: B(0) DMA + A(0) gen
    #pragma unroll
    for (int it = 0; it < 2; ++it) {
        int id = it * THR2 + tid;
        glds16(Wsw + id * 8, &smem[OFF_B0 + id * 8]);
    }
    gen_elem(xc, hinv, b0, &smem[OFF_A0 + awr]);
    __syncthreads();

    for (int kb = 0; kb < NCH2; ++kb) {
        const int cur = kb & 1;
        if (kb + 1 < NCH2) {
            const unsigned short* wc = Wsw + (size_t)(kb + 1) * B2SZ;
            unsigned boff = cur ? OFF_B0 : OFF_B1;   // next buffer
            #pragma unroll
            for (int it = 0; it < 2; ++it) {
                int id = it * THR2 + tid;
                glds16(wc + id * 8, &smem[boff + id * 8]);
            }
            unsigned short xh = xn;
            if (kb + 2 < NCH2) xn = xp[(kb + 2) * 4];
            gen_elem(xh, hinv, b0, &smem[(cur ? OFF_A0 : OFF_A1) + awr]);
        }
        // MFMA on current buffers
        const unsigned ab = cur ? OFF_A1 : OFF_A0;
        const unsigned bb = cur ? OFF_B1 : OFF_B0;
        bf16x8 af[4], bfr[4];
        #pragma unroll
        for (int mt = 0; mt < 4; ++mt)
            af[mt] = *(const bf16x8*)&smem[ab + (m0 + mt*16 + lrow) * A2STR + lquad * 8];
        #pragma unroll
        for (int nt = 0; nt < 4; ++nt) {
            int n = n0 + nt * 16 + lrow;
            bfr[nt] = *(const bf16x8*)&smem[bb + n * 32 + ((((n >> 1) + lquad) & 3) << 3)];
        }
        #pragma unroll
        for (int mt = 0; mt < 4; ++mt)
            #pragma unroll
            for (int nt = 0; nt < 4; ++nt)
                acc[mt][nt] = __builtin_amdgcn_mfma_f32_16x16x32_bf16(
                    af[mt], bfr[nt], acc[mt][nt], 0, 0, 0);
        __syncthreads();
    }

    // epilogue: C row = edge (m), col = out (n)
    #pragma unroll
    for (int mt = 0; mt < 4; ++mt) {
        #pragma unroll
        for (int r = 0; r < 4; ++r) {
            int row = m0 + mt * 16 + lquad * 4 + r;
            int eg  = e_base + row;
            if (eg < NEDGES) {
                float* op = out + (size_t)eg * OUT_DIM + n0 + lrow;
                #pragma unroll
                for (int nt = 0; nt < 4; ++nt)
                    op[nt * 16] = acc[mt][nt][r];
            }
        }
    }
}

// =====================================================================
// FALLBACK (no workspace): round-1 fused kernel, correctness-only
// =====================================================================
#define XSTR 392
#define FSTR 72
#define FOFF_X 0
#define FOFF_A (128 * XSTR)
#define FOFF_B (FOFF_A + 128 * FSTR)
#define FLDS (FOFF_B + OUT_DIM * FSTR)

__global__ __launch_bounds__(512, 2)
void fused_fallback(const float* __restrict__ node_emb,
                    const float* __restrict__ ctx_emb,
                    const int*   __restrict__ pair,
                    const float* __restrict__ ctx_w,
                    const float* __restrict__ ctx_b,
                    const float* __restrict__ base_w,
                    const float* __restrict__ spline_w,
                    const float* __restrict__ spline_s,
                    const float* __restrict__ grid,
                    float* __restrict__ out)
{
    __shared__ unsigned short smem[FLDS];
    const int tid    = threadIdx.x;
    const int e_base = blockIdx.x * 128;
    const int wid    = tid >> 6;
    const int lan    = tid & 63;
    const int lrow   = lan & 15;
    const int lquad  = lan >> 4;

    #pragma unroll
    for (int it = 0; it < 16; ++it) {
        int id    = it * 512 + tid;
        int lane4 = id & 31;
        int e     = (id >> 5) & 127;
        int which = id >> 12;
        int eg = e_base + e; if (eg >= NEDGES) eg = NEDGES - 1;
        int node = pair[eg * 2 + which];
        const float4 v = *(const float4*)(node_emb + (size_t)node * NODE_DIM + lane4 * 4);
        *(ushort4*)&smem[FOFF_X + e * XSTR + which * NODE_DIM + lane4 * 4] =
            make_ushort4(f2bf(v.x), f2bf(v.y), f2bf(v.z), f2bf(v.w));
    }
    {
        f32x4 cacc[4][2];
        #pragma unroll
        for (int a = 0; a < 4; ++a)
            #pragma unroll
            for (int b = 0; b < 2; ++b) { f32x4 z = {0.f,0.f,0.f,0.f}; cacc[a][b] = z; }
        const int m0 = (wid & 1) * 64;
        const int n0 = (wid >> 1) * 32;
        for (int kc = 0; kc < 4; ++kc) {
            #pragma unroll
            for (int it = 0; it < 4; ++it) {
                int id = it * 512 + tid;
                int r  = id >> 4;
                int c4 = id & 15;
                int eg = e_base + r; if (eg >= NEDGES) eg = NEDGES - 1;
                float4 v = *(const float4*)(ctx_emb + (size_t)eg * CTX_DIM + kc * 64 + c4 * 4);
                *(ushort4*)&smem[FOFF_A + r * FSTR + c4 * 4] =
                    make_ushort4(f2bf(v.x), f2bf(v.y), f2bf(v.z), f2bf(v.w));
                float4 w = *(const float4*)(ctx_w + (size_t)r * CTX_DIM + kc * 64 + c4 * 4);
                *(ushort4*)&smem[FOFF_B + r * FSTR + c4 * 4] =
                    make_ushort4(f2bf(w.x), f2bf(w.y), f2bf(w.z), f2bf(w.w));
            }
            __syncthreads();
            #pragma unroll
            for (int ks = 0; ks < 2; ++ks) {
                int koff = ks * 32 + lquad * 8;
                bf16x8 af[4], bfr[2];
                #pragma unroll
                for (int mt = 0; mt < 4; ++mt)
                    af[mt] = *(const bf16x8*)&smem[FOFF_A + (m0 + mt*16 + lrow) * FSTR + koff];
                #pragma unroll
                for (int nt = 0; nt < 2; ++nt)
                    bfr[nt] = *(const bf16x8*)&smem[FOFF_B + (n0 + nt*16 + lrow) * FSTR + koff];
                #pragma unroll
                for (int mt = 0; mt < 4; ++mt)
                    #pragma unroll
                    for (int nt = 0; nt < 2; ++nt)
                        cacc[mt][nt] = __builtin_amdgcn_mfma_f32_16x16x32_bf16(
                            af[mt], bfr[nt], cacc[mt][nt], 0, 0, 0);
            }
            __syncthreads();
        }
        #pragma unroll
        for (int mt = 0; mt < 4; ++mt)
            #pragma unroll
            for (int nt = 0; nt < 2; ++nt)
                #pragma unroll
                for (int r = 0; r < 4; ++r) {
                    int row = m0 + mt*16 + lquad*4 + r;
                    int col = n0 + nt*16 + lrow;
                    smem[FOFF_X + row * XSTR + 256 + col] = f2bf(cacc[mt][nt][r] + ctx_b[col]);
                }
    }
    __syncthreads();

    const float g0   = grid[0];
    const float hinv = 1.0f / (grid[1] - grid[0]);

    f32x4 acc[4][4];
    #pragma unroll
    for (int a = 0; a < 4; ++a)
        #pragma unroll
        for (int b = 0; b < 4; ++b) { f32x4 z = {0.f,0.f,0.f,0.f}; acc[a][b] = z; }

    const int m0 = (wid & 1) * 64;
    const int n0 = (wid >> 1) * 64;

    for (int kb = 0; kb < 48; ++kb) {
        const int seg = kb / 6;
        const int i0  = (kb - seg * 6) * 64;
        #pragma unroll
        for (int it = 0; it < 4; ++it) {
            int id = it * 512 + tid;
            int e  = id >> 4;
            int qq = id & 15;
            ushort4 xv = *(const ushort4*)&smem[FOFF_X + e * XSTR + i0 + qq * 4];
            float x0 = bf2f(xv.x), x1 = bf2f(xv.y), x2 = bf2f(xv.z), x3 = bf2f(xv.w);
            unsigned short r0, r1, r2, r3;
            if (seg == 0) {
                r0 = f2bf(silu(x0)); r1 = f2bf(silu(x1));
                r2 = f2bf(silu(x2)); r3 = f2bf(silu(x3));
            } else {
                const float cf = (float)(seg - 1);
                r0 = f2bf(n3((x0 - g0) * hinv - cf));
                r1 = f2bf(n3((x1 - g0) * hinv - cf));
                r2 = f2bf(n3((x2 - g0) * hinv - cf));
                r3 = f2bf(n3((x3 - g0) * hinv - cf));
            }
            *(ushort4*)&smem[FOFF_A + e * FSTR + qq * 4] = make_ushort4(r0, r1, r2, r3);
        }
        #pragma unroll
        for (int it = 0; it < 4; ++it) {
            int id = it * 512 + tid;
            int o  = id >> 4;
            int qq = id & 15;
            unsigned short r0, r1, r2, r3;
            if (seg == 0) {
                const float4 w = *(const float4*)(base_w + (size_t)o * IN_DIM + i0 + qq * 4);
                r0 = f2bf(w.x); r1 = f2bf(w.y); r2 = f2bf(w.z); r3 = f2bf(w.w);
            } else {
                int c  = seg - 1;
                int bi = o * IN_DIM + i0 + qq * 4;
                r0 = f2bf(spline_w[(size_t)(bi    ) * NCOEF + c] * spline_s[bi    ]);
                r1 = f2bf(spline_w[(size_t)(bi + 1) * NCOEF + c] * spline_s[bi + 1]);
                r2 = f2bf(spline_w[(size_t)(bi + 2) * NCOEF + c] * spline_s[bi + 2]);
                r3 = f2bf(spline_w[(size_t)(bi + 3) * NCOEF + c] * spline_s[bi + 3]);
            }
            *(ushort4*)&smem[FOFF_B + o * FSTR + qq * 4] = make_ushort4(r0, r1, r2, r3);
        }
        __syncthreads();
        #pragma unroll
        for (int ks = 0; ks < 2; ++ks) {
            int koff = ks * 32 + lquad * 8;
            bf16x8 af[4], bfr[4];
            #pragma unroll
            for (int mt = 0; mt < 4; ++mt)
                af[mt] = *(const bf16x8*)&smem[FOFF_A + (m0 + mt*16 + lrow) * FSTR + koff];
            #pragma unroll
            for (int nt = 0; nt < 4; ++nt)
                bfr[nt] = *(const bf16x8*)&smem[FOFF_B + (n0 + nt*16 + lrow) * FSTR + koff];
            #pragma unroll
            for (int mt = 0; mt < 4; ++mt)
                #pragma unroll
                for (int nt = 0; nt < 4; ++nt)
                    acc[mt][nt] = __builtin_amdgcn_mfma_f32_16x16x32_bf16(
                        af[mt], bfr[nt], acc[mt][nt], 0, 0, 0);
        }
        __syncthreads();
    }

    #pragma unroll
    for (int mt = 0; mt < 4; ++mt) {
        #pragma unroll
        for (int r = 0; r < 4; ++r) {
            int row = m0 + mt*16 + lquad*4 + r;
            int eg  = e_base + row;
            if (eg < NEDGES) {
                float* op = out + (size_t)eg * OUT_DIM + n0 + lrow;
                #pragma unroll
                for (int nt = 0; nt < 4; ++nt)
                    op[nt * 16] = acc[mt][nt][r];
            }
        }
    }
}

// ---------------- launch ----------------
extern "C" void kernel_launch(void* const* d_in, const int* in_sizes, int n_in,
                              void* d_out, int out_size, void* d_ws, size_t ws_size,
                              hipStream_t stream)
{
    const float* node_emb = (const float*)d_in[0];
    const float* ctx_emb  = (const float*)d_in[1];
    const int*   pair     = (const int*)d_in[2];
    const float* ctx_w    = (const float*)d_in[3];
    const float* ctx_b    = (const float*)d_in[4];
    const float* base_w   = (const float*)d_in[5];
    const float* spline_w = (const float*)d_in[6];
    const float* spline_s = (const float*)d_in[7];
    const float* grid     = (const float*)d_in[8];
    float* out = (float*)d_out;

    const int nblk = (NEDGES + BM2 - 1) / BM2;     // 782
    const size_t xoff = 2u * 1024u * 1024u;
    const size_t need = xoff + (size_t)NEDGES * IN_DIM * sizeof(unsigned short);

    if (ws_size >= need) {
        unsigned short* Wsw = (unsigned short*)d_ws;
        unsigned short* Xbf = (unsigned short*)((char*)d_ws + xoff);
        prep_w2<<<OUT_DIM, IN_DIM, 0, stream>>>(base_w, spline_w, spline_s, Wsw);
        build_x<<<nblk, 512, 0, stream>>>(node_emb, ctx_emb, pair, ctx_w, ctx_b, Xbf);
        kan_gemm2<<<nblk, THR2, 0, stream>>>(Wsw, Xbf, grid, out);
    } else {
        fused_fallback<<<nblk, 512, 0, stream>>>(
            node_emb, ctx_emb, pair, ctx_w, ctx_b, base_w, spline_w, spline_s, grid, out);
    }
}